// Round 2
// baseline (269.533 us; speedup 1.0000x reference)
//
#include <hip/hip_runtime.h>
#include <hip/hip_bf16.h>
#include <stdint.h>

#define LQ 2048
#define LK 2048
#define DH 128
#define BQ 64          // q rows per workgroup
#define KB 128         // keys per staged tile
#define NT (LK / KB)   // 16 iterations
#define KROW 136       // LDS row stride in bf16 elems (272 B => 17x16B granules/row, odd -> conflict-free b128 reads)
#define LOG2E 1.44269504088896340736f
#define QSCALE 0.088388347648318447f   // 1/sqrt(128)

typedef __attribute__((ext_vector_type(8)))  short bf16x8;
typedef __attribute__((ext_vector_type(16))) float f32x16;
typedef __attribute__((ext_vector_type(4)))  float f32x4;

union FragAB { uint32_t u[4]; bf16x8 v; };

__device__ __forceinline__ uint32_t pack2_bf16(float lo, float hi) {
  union { __hip_bfloat16 b; uint16_t u; } a, c;
  a.b = __float2bfloat16(lo);
  c.b = __float2bfloat16(hi);
  return (uint32_t)a.u | ((uint32_t)c.u << 16);
}

// ============================================================================
// Pre-pass 1: dropout keep-mask bits. mask[b][q][ks][t] dwords (bit k&31 of
// the (t*4+ks)-th 32-key group of row (b,q)). 4 MB total -> L2-resident.
// ============================================================================
__global__ __launch_bounds__(256)
void mask_kernel(const float* __restrict__ uu, uint32_t* __restrict__ maskp) {
  const int lane = threadIdx.x & 63;
  const int wid  = blockIdx.x * 4 + (threadIdx.x >> 6);  // 8192 waves
#pragma unroll 1
  for (int i = 0; i < 16; ++i) {
    const size_t F = ((size_t)i * 8192 + wid) * 256;   // 256 consecutive floats per wave-iter
    float u0 = uu[F + 0 * 64 + lane];
    float u1 = uu[F + 1 * 64 + lane];
    float u2 = uu[F + 2 * 64 + lane];
    float u3 = uu[F + 3 * 64 + lane];
    uint64_t B0 = __ballot(u0 >= 0.1f);
    uint64_t B1 = __ballot(u1 >= 0.1f);
    uint64_t B2 = __ballot(u2 >= 0.1f);
    uint64_t B3 = __ballot(u3 >= 0.1f);
    if (lane < 8) {
      const int m = lane;
      uint64_t bb = (m < 2) ? B0 : (m < 4) ? B1 : (m < 6) ? B2 : B3;
      uint32_t val = (m & 1) ? (uint32_t)(bb >> 32) : (uint32_t)bb;
      const size_t row = F >> 11;                 // composite (b*2048+q)
      const int c = (int)((F >> 5) & 63) + m;     // k32 index in row
      maskp[row * 64 + (size_t)((c & 3) * 16 + (c >> 2))] = val;  // [ks][t] order
    }
  }
}

// ============================================================================
// Pre-pass 2: qm * LOG2E -> bf16, packed in per-lane fragment order:
// qmt2[(kc*2+h)][q][gi 0..15] bf16, where kc = k>>5, h=(k>>2)&1,
// gi = (k5>>3)*4 + (k&3), k5=k&31.  8 MB.
// ============================================================================
__global__ __launch_bounds__(256)
void qmt_kernel(const float* __restrict__ qm, uint16_t* __restrict__ qmt2) {
  const int kc = threadIdx.x & 63;
  const int q  = blockIdx.x * 4 + (threadIdx.x >> 6);
  f32x4 r[8];
  const float* src = qm + (size_t)q * 2048 + kc * 32;
#pragma unroll
  for (int c = 0; c < 8; ++c) r[c] = *(const f32x4*)(src + c * 4);
#pragma unroll
  for (int h = 0; h < 2; ++h) {
    uint32_t w[8];
#pragma unroll
    for (int i = 0; i < 8; ++i) {
      const int gi0 = 2 * i, gi1 = 2 * i + 1;
      const float v0 = r[h + (gi0 >> 2) * 2][gi0 & 3] * LOG2E;
      const float v1 = r[h + (gi1 >> 2) * 2][gi1 & 3] * LOG2E;
      w[i] = pack2_bf16(v0, v1);
    }
    uint16_t* dst = qmt2 + ((size_t)(kc * 2 + h) * 2048 + q) * 16;
    uint4 lo = {w[0], w[1], w[2], w[3]};
    uint4 hi = {w[4], w[5], w[6], w[7]};
    *(uint4*)dst = lo;
    *(uint4*)(dst + 8) = hi;
  }
}

// ============================================================================
// Main flash-attention kernel (swapped-operand MFMA, per-lane softmax state)
// ============================================================================
__device__ __forceinline__ void stage_writes(uint16_t* Kb, uint16_t* Vb,
                                             const f32x4* st, int sbi, int sbj) {
#pragma unroll
  for (int j = 0; j < 2; ++j) {
    const int rowb = 4 * (sbi + 16 * j);
#pragma unroll
    for (int r = 0; r < 4; ++r) {       // K[key][d] row-major bf16 (8B store)
      f32x4 v = st[j * 4 + r];
      uint64_t pk = (uint64_t)pack2_bf16(v.x, v.y) |
                    ((uint64_t)pack2_bf16(v.z, v.w) << 32);
      *(uint64_t*)(Kb + (size_t)(rowb + r) * KROW + 4 * sbj) = pk;
    }
#pragma unroll
    for (int c = 0; c < 4; ++c) {       // Vt[d][key] transposed bf16 (8B store)
      uint64_t pv = (uint64_t)pack2_bf16(st[j * 4 + 0][c], st[j * 4 + 1][c]) |
                    ((uint64_t)pack2_bf16(st[j * 4 + 2][c], st[j * 4 + 3][c]) << 32);
      *(uint64_t*)(Vb + (size_t)(4 * sbj + c) * KROW + rowb) = pv;
    }
  }
}

__global__ __launch_bounds__(512, 2)
void fattn_kernel(const float* __restrict__ x1, const float* __restrict__ x2,
                  const uint32_t* __restrict__ maskp,
                  const uint16_t* __restrict__ qmt2,
                  float* __restrict__ out)
{
  __shared__ uint16_t ldsK[2][128 * KROW];   // 69632 B
  __shared__ uint16_t ldsV[2][128 * KROW];   // 69632 B  (total 136 KB)

  const int tid  = threadIdx.x;
  const int wv   = tid >> 6;
  const int lane = tid & 63;
  const int ln   = lane & 31;
  const int h    = lane >> 5;
  const int qsub = wv & 1;    // which 32-row q subtile
  const int ks   = wv >> 1;   // k-split index 0..3

  const int b    = blockIdx.x & 7;    // batch -> XCD locality for x2 slice
  const int qblk = blockIdx.x >> 3;
  const int qrow = qblk * BQ + qsub * 32 + ln;   // this lane's q row

  // ---- Q fragments (B-operand of S^T mfma), scaled by QSCALE*LOG2E
  FragAB qf[8];
  {
    const float* qp = x1 + ((size_t)(b * LQ + qrow)) * DH + h * 8;
    const float qs = QSCALE * LOG2E;
#pragma unroll
    for (int dc = 0; dc < 8; ++dc) {
      f32x4 a = *(const f32x4*)(qp + dc * 16);
      f32x4 c = *(const f32x4*)(qp + dc * 16 + 4);
      qf[dc].u[0] = pack2_bf16(a.x * qs, a.y * qs);
      qf[dc].u[1] = pack2_bf16(a.z * qs, a.w * qs);
      qf[dc].u[2] = pack2_bf16(c.x * qs, c.y * qs);
      qf[dc].u[3] = pack2_bf16(c.z * qs, c.w * qs);
    }
  }

  const int sbi = tid >> 5;   // staging: 4-row group
  const int sbj = tid & 31;   // staging: 4-col group
  const float* x2base = x2 + (size_t)b * LK * DH + sbj * 4;
  const uint32_t* maskrow = maskp + ((size_t)(b * LQ + qrow)) * 64 + ks * 16;

  // ---- stage tile 0
  f32x4 st[8];
#pragma unroll
  for (int j = 0; j < 2; ++j)
#pragma unroll
    for (int r = 0; r < 4; ++r)
      st[j * 4 + r] = *(const f32x4*)(x2base + (size_t)(4 * (sbi + 16 * j) + r) * DH);

  uint32_t mcur = maskrow[0];
  uint4 qc0, qc1;
  {
    const uint16_t* qp16 = qmt2 + (((size_t)(0 * 4 + ks) * 2 + h) * 2048 + qrow) * 16;
    qc0 = *(const uint4*)qp16;
    qc1 = *(const uint4*)(qp16 + 8);
  }

  stage_writes(ldsK[0], ldsV[0], st, sbi, sbj);
  __syncthreads();

  float m_run = -1e30f, l_run = 0.f;
  f32x16 acco[4];
#pragma unroll
  for (int d2 = 0; d2 < 4; ++d2)
#pragma unroll
    for (int i = 0; i < 16; ++i) acco[d2][i] = 0.f;

  for (int t = 0; t < NT; ++t) {
    const int cb = t & 1;
    const uint16_t* Kb = ldsK[cb];
    const uint16_t* Vb = ldsV[cb];
    const int kb = t * KB;

    // ---- prefetch next x2 tile + next mask/qm (in flight across compute)
    uint32_t mnxt = 0; uint4 qn0, qn1;
    if (t + 1 < NT) {
#pragma unroll
      for (int j = 0; j < 2; ++j)
#pragma unroll
        for (int r = 0; r < 4; ++r)
          st[j * 4 + r] = *(const f32x4*)(x2base + (size_t)(kb + KB + 4 * (sbi + 16 * j) + r) * DH);
      mnxt = maskrow[t + 1];
      const uint16_t* qp16 = qmt2 + (((size_t)((t + 1) * 4 + ks) * 2 + h) * 2048 + qrow) * 16;
      qn0 = *(const uint4*)qp16;
      qn1 = *(const uint4*)(qp16 + 8);
    }

    // ---- QK: S^T(32k x 32q) = K(32k x 16d) * Q^T(16d x 32q)
    f32x16 sacc;
#pragma unroll
    for (int i = 0; i < 16; ++i) sacc[i] = 0.f;
    const uint16_t* Krow = Kb + (size_t)(ks * 32 + ln) * KROW + h * 8;
#pragma unroll
    for (int dc = 0; dc < 8; ++dc) {
      bf16x8 af = *(const bf16x8*)(Krow + dc * 16);
      sacc = __builtin_amdgcn_mfma_f32_32x32x16_bf16(af, qf[dc].v, sacc, 0, 0, 0);
    }

    // ---- add qm*LOG2E (bf16 pre-packed in fragment order)
#define ADDQM(W, I) { sacc[I] += __uint_as_float((W) << 16); \
                      sacc[I + 1] += __uint_as_float((W) & 0xffff0000u); }
    ADDQM(qc0.x, 0)  ADDQM(qc0.y, 2)  ADDQM(qc0.z, 4)  ADDQM(qc0.w, 6)
    ADDQM(qc1.x, 8)  ADDQM(qc1.y, 10) ADDQM(qc1.z, 12) ADDQM(qc1.w, 14)
#undef ADDQM

    // ---- online softmax (log2 domain; lane owns q-row)
    float pm = sacc[0];
#pragma unroll
    for (int i = 1; i < 16; ++i) pm = fmaxf(pm, sacc[i]);
    pm = fmaxf(pm, __shfl_xor(pm, 32));
    const float mnew = fmaxf(m_run, pm);
    const float resc = __builtin_amdgcn_exp2f(m_run - mnew);
    m_run = mnew;
    float rs = 0.f;
#pragma unroll
    for (int i = 0; i < 16; ++i) {
      sacc[i] = __builtin_amdgcn_exp2f(sacc[i] - mnew);
      rs += sacc[i];
    }
    rs += __shfl_xor(rs, 32);
    l_run = l_run * resc + rs;          // denominator WITHOUT dropout

    // ---- dropout on numerator from bitmask (bit = h*4 + g*8 + j)
#pragma unroll
    for (int g = 0; g < 4; ++g)
#pragma unroll
      for (int j2 = 0; j2 < 4; ++j2) {
        const uint32_t keep = (mcur >> (h * 4 + g * 8 + j2)) & 1u;
        sacc[g * 4 + j2] = keep ? sacc[g * 4 + j2] : 0.f;
      }

    // ---- pack bf16 pairs + exchange key-halves across lane-32 boundary
    uint32_t pr[4][2], sw[4][2];
#pragma unroll
    for (int g = 0; g < 4; ++g) {
      pr[g][0] = pack2_bf16(sacc[4 * g + 0], sacc[4 * g + 1]);
      pr[g][1] = pack2_bf16(sacc[4 * g + 2], sacc[4 * g + 3]);
      sw[g][0] = __shfl_xor(pr[g][0], 32);
      sw[g][1] = __shfl_xor(pr[g][1], 32);
    }
    FragAB bfr[2];
#pragma unroll
    for (int c = 0; c < 2; ++c) {
      bfr[c].u[0] = h ? sw[2 * c + 1][0] : pr[2 * c][0];
      bfr[c].u[1] = h ? sw[2 * c + 1][1] : pr[2 * c][1];
      bfr[c].u[2] = h ? pr[2 * c + 1][0] : sw[2 * c][0];
      bfr[c].u[3] = h ? pr[2 * c + 1][1] : sw[2 * c][1];
    }

    // ---- rescale running accumulator
#pragma unroll
    for (int d2 = 0; d2 < 4; ++d2)
#pragma unroll
      for (int i = 0; i < 16; ++i) acco[d2][i] *= resc;

    // ---- PV: out^T(32d x 32q) += V^T(32d x 16k) * P(16k x 32q)
#pragma unroll
    for (int d2 = 0; d2 < 4; ++d2) {
      const uint16_t* Vrow = Vb + (size_t)(d2 * 32 + ln) * KROW + ks * 32 + h * 8;
#pragma unroll
      for (int c = 0; c < 2; ++c) {
        bf16x8 av = *(const bf16x8*)(Vrow + c * 16);
        acco[d2] = __builtin_amdgcn_mfma_f32_32x32x16_bf16(av, bfr[c].v, acco[d2], 0, 0, 0);
      }
    }

    // ---- write next tile into other buffer, single barrier per iter
    if (t + 1 < NT) {
      stage_writes(ldsK[cb ^ 1], ldsV[cb ^ 1], st, sbi, sbj);
      mcur = mnxt; qc0 = qn0; qc1 = qn1;
    }
    __syncthreads();
  }

  // ---- k-split merge through LDS
  float* scr = (wv < 4) ? ((float*)ldsK + (size_t)wv * 4224)
                        : ((float*)ldsV + (size_t)(wv - 4) * 4224);
  scr[lane]      = m_run;
  scr[64 + lane] = l_run;
#pragma unroll
  for (int d2 = 0; d2 < 4; ++d2)
#pragma unroll
    for (int g = 0; g < 4; ++g) {
      f32x4 vv;
#pragma unroll
      for (int j2 = 0; j2 < 4; ++j2) vv[j2] = acco[d2][g * 4 + j2];
      *(f32x4*)(scr + 128 + (size_t)(d2 * 4 + g) * 256 + lane * 4) = vv;
    }
  __syncthreads();

  if (wv < 2) {
    const float* rg[4];
#pragma unroll
    for (int s2 = 0; s2 < 4; ++s2) {
      const int r = qsub + 2 * s2;
      rg[s2] = (r < 4) ? ((const float*)ldsK + (size_t)r * 4224)
                       : ((const float*)ldsV + (size_t)(r - 4) * 4224);
    }
    const float ms0 = rg[0][lane], ms1 = rg[1][lane], ms2 = rg[2][lane], ms3 = rg[3][lane];
    const float ls0 = rg[0][64 + lane], ls1 = rg[1][64 + lane];
    const float ls2 = rg[2][64 + lane], ls3 = rg[3][64 + lane];
    const float mM = fmaxf(fmaxf(ms0, ms1), fmaxf(ms2, ms3));
    const float e0 = __builtin_amdgcn_exp2f(ms0 - mM);
    const float e1 = __builtin_amdgcn_exp2f(ms1 - mM);
    const float e2 = __builtin_amdgcn_exp2f(ms2 - mM);
    const float e3 = __builtin_amdgcn_exp2f(ms3 - mM);
    const float lM = e0 * ls0 + e1 * ls1 + e2 * ls2 + e3 * ls3;
    const float inv = (1.0f / 0.9f) / lM;   // fold dropout 1/(1-p) into normalization
    float* op = out + ((size_t)(b * LQ + qrow)) * DH;
#pragma unroll
    for (int d2 = 0; d2 < 4; ++d2)
#pragma unroll
      for (int g = 0; g < 4; ++g) {
        const size_t off = 128 + (size_t)(d2 * 4 + g) * 256 + lane * 4;
        f32x4 a4 = e0 * *(const f32x4*)(rg[0] + off)
                 + e1 * *(const f32x4*)(rg[1] + off)
                 + e2 * *(const f32x4*)(rg[2] + off)
                 + e3 * *(const f32x4*)(rg[3] + off);
        a4 = a4 * inv;
        *(f32x4*)(op + d2 * 32 + 8 * g + 4 * h) = a4;
      }
  }
}

extern "C" void kernel_launch(void* const* d_in, const int* in_sizes, int n_in,
                              void* d_out, int out_size, void* d_ws, size_t ws_size,
                              hipStream_t stream) {
  (void)in_sizes; (void)n_in; (void)out_size; (void)ws_size;
  const float* x1 = (const float*)d_in[0];
  const float* x2 = (const float*)d_in[1];
  const float* qm = (const float*)d_in[2];
  const float* u  = (const float*)d_in[3];
  float* out = (float*)d_out;

  uint32_t* maskp = (uint32_t*)d_ws;                          // 4 MB
  uint16_t* qmt2  = (uint16_t*)((char*)d_ws + (4u << 20));    // 8 MB

  mask_kernel<<<dim3(2048), dim3(256), 0, stream>>>(u, maskp);
  qmt_kernel<<<dim3(512), dim3(256), 0, stream>>>(qm, qmt2);
  fattn_kernel<<<dim3(256), dim3(512), 0, stream>>>(x1, x2, maskp, qmt2, out);
}

// Round 3
// 245.061 us; speedup vs baseline: 1.0999x; 1.0999x over previous
//
#include <hip/hip_runtime.h>
#include <hip/hip_bf16.h>
#include <stdint.h>

#define LQ 2048
#define LK 2048
#define DH 128
#define BQ 64          // q rows per workgroup
#define KB 128         // keys per staged tile
#define NT (LK / KB)   // 16 iterations
#define KROW 136       // LDS row stride in bf16 elems (272 B = 17x16B granules, odd -> conflict-free b128 reads)
#define LOG2E 1.44269504088896340736f
#define QSCALE 0.088388347648318447f   // 1/sqrt(128)

typedef __attribute__((ext_vector_type(8)))  short bf16x8;
typedef __attribute__((ext_vector_type(16))) float f32x16;
typedef __attribute__((ext_vector_type(4)))  float f32x4;

union FragAB { uint32_t u[4]; bf16x8 v; };

__device__ __forceinline__ uint32_t pack2_bf16(float lo, float hi) {
  union { __hip_bfloat16 b; uint16_t u; } a, c;
  a.b = __float2bfloat16(lo);
  c.b = __float2bfloat16(hi);
  return (uint32_t)a.u | ((uint32_t)c.u << 16);
}

// ============================================================================
// Pre-pass: qm * LOG2E -> bf16, packed in per-lane fragment order:
// qmt2[(kc*2+h)][q][gi 0..15] bf16, kc = k>>5, h=(k>>2)&1, gi=(k5>>3)*4+(k&3)
// ============================================================================
__global__ __launch_bounds__(256)
void qmt_kernel(const float* __restrict__ qm, uint16_t* __restrict__ qmt2) {
  const int kc = threadIdx.x & 63;
  const int q  = blockIdx.x * 4 + (threadIdx.x >> 6);
  f32x4 r[8];
  const float* src = qm + (size_t)q * 2048 + kc * 32;
#pragma unroll
  for (int c = 0; c < 8; ++c) r[c] = *(const f32x4*)(src + c * 4);
#pragma unroll
  for (int h = 0; h < 2; ++h) {
    uint32_t w[8];
#pragma unroll
    for (int i = 0; i < 8; ++i) {
      const int gi0 = 2 * i, gi1 = 2 * i + 1;
      const float v0 = r[h + (gi0 >> 2) * 2][gi0 & 3] * LOG2E;
      const float v1 = r[h + (gi1 >> 2) * 2][gi1 & 3] * LOG2E;
      w[i] = pack2_bf16(v0, v1);
    }
    uint16_t* dst = qmt2 + ((size_t)(kc * 2 + h) * 2048 + q) * 16;
    uint4 lo = {w[0], w[1], w[2], w[3]};
    uint4 hi = {w[4], w[5], w[6], w[7]};
    *(uint4*)dst = lo;
    *(uint4*)(dst + 8) = hi;
  }
}

// ============================================================================
// Main flash-attention kernel
// ============================================================================
__device__ __forceinline__ void stage_writes(uint16_t* Kb, uint16_t* Vb,
                                             const f32x4* st, int sbi, int sbj) {
#pragma unroll
  for (int j = 0; j < 2; ++j) {
    const int rowb = 4 * (sbi + 16 * j);
#pragma unroll
    for (int r = 0; r < 4; ++r) {       // K[key][d] row-major bf16 (8B store)
      f32x4 v = st[j * 4 + r];
      uint64_t pk = (uint64_t)pack2_bf16(v.x, v.y) |
                    ((uint64_t)pack2_bf16(v.z, v.w) << 32);
      *(uint64_t*)(Kb + (size_t)(rowb + r) * KROW + 4 * sbj) = pk;
    }
#pragma unroll
    for (int c = 0; c < 4; ++c) {       // Vt[d][key] transposed bf16 (8B store)
      uint64_t pv = (uint64_t)pack2_bf16(st[j * 4 + 0][c], st[j * 4 + 1][c]) |
                    ((uint64_t)pack2_bf16(st[j * 4 + 2][c], st[j * 4 + 3][c]) << 32);
      // XOR swizzle ((d>>2)&7)<<3 elems: write 16-way conflict -> 4-way,
      // read side stays conflict-free (Gray-code phase).
      const size_t off = ((size_t)(4 * sbj + c) * KROW + rowb) ^ (size_t)((sbj & 7) << 3);
      *(uint64_t*)(Vb + off) = pv;
    }
  }
}

__global__ __launch_bounds__(512, 2)
void fattn_kernel(const float* __restrict__ x1, const float* __restrict__ x2,
                  const float* __restrict__ uu,
                  const uint16_t* __restrict__ qmt2,
                  float* __restrict__ out)
{
  __shared__ uint16_t ldsK[2][128 * KROW];   // 69632 B
  __shared__ uint16_t ldsV[2][128 * KROW];   // 69632 B  (total 136 KB)

  const int tid  = threadIdx.x;
  const int wv   = tid >> 6;
  const int lane = tid & 63;
  const int ln   = lane & 31;
  const int h    = lane >> 5;
  const int qsub = wv & 1;    // which 32-row q subtile
  const int ks   = wv >> 1;   // k-split index 0..3

  const int b    = blockIdx.x & 7;    // batch -> XCD locality for x2 slice
  const int qblk = blockIdx.x >> 3;
  const int qbase = qblk * BQ + qsub * 32;
  const int qrow  = qbase + ln;       // this lane's q row

  // ---- Q fragments (B-operand of S^T mfma), scaled by QSCALE*LOG2E
  FragAB qf[8];
  {
    const float* qp = x1 + ((size_t)(b * LQ + qrow)) * DH + h * 8;
    const float qs = QSCALE * LOG2E;
#pragma unroll
    for (int dc = 0; dc < 8; ++dc) {
      f32x4 a = *(const f32x4*)(qp + dc * 16);
      f32x4 c = *(const f32x4*)(qp + dc * 16 + 4);
      qf[dc].u[0] = pack2_bf16(a.x * qs, a.y * qs);
      qf[dc].u[1] = pack2_bf16(a.z * qs, a.w * qs);
      qf[dc].u[2] = pack2_bf16(c.x * qs, c.y * qs);
      qf[dc].u[3] = pack2_bf16(c.z * qs, c.w * qs);
    }
  }

  const int sbi = tid >> 5;   // staging: 4-row group (0..15)
  const int sbj = tid & 31;   // staging: 4-col group
  const float* x2base = x2 + (size_t)b * LK * DH + sbj * 4;
  // u: lane l covers rows (qbase + 2i + h), key column (ks*32 + ln)
  const float* ub = uu + ((size_t)(b * LQ + qbase + h)) * LK + ks * 32 + ln;
  const int vxor = ((ln >> 2) & 7) << 3;   // Vt read-side swizzle (per-lane const)

  // ---- stage tile 0
  f32x4 st[8];
#pragma unroll
  for (int j = 0; j < 2; ++j)
#pragma unroll
    for (int r = 0; r < 4; ++r)
      st[j * 4 + r] = *(const f32x4*)(x2base + (size_t)(4 * (sbi + 16 * j) + r) * DH);

  float ucur[16];
#pragma unroll
  for (int i = 0; i < 16; ++i)
    ucur[i] = __builtin_nontemporal_load(ub + (size_t)(2 * i) * LK);

  uint4 qc0, qc1;
  {
    const uint16_t* qp16 = qmt2 + (((size_t)(0 * 4 + ks) * 2 + h) * 2048 + qrow) * 16;
    qc0 = *(const uint4*)qp16;
    qc1 = *(const uint4*)(qp16 + 8);
  }

  stage_writes(ldsK[0], ldsV[0], st, sbi, sbj);
  __syncthreads();

  float m_run = -1e30f, l_run = 0.f;
  f32x16 acco[4];
#pragma unroll
  for (int d2 = 0; d2 < 4; ++d2)
#pragma unroll
    for (int i = 0; i < 16; ++i) acco[d2][i] = 0.f;

  for (int t = 0; t < NT; ++t) {
    const int cb = t & 1;
    const uint16_t* Kb = ldsK[cb];
    const uint16_t* Vb = ldsV[cb];
    const int kb = t * KB;

    // ---- prefetch next x2 tile + next u/qm (in flight across compute)
    float unxt[16]; uint4 qn0, qn1;
    if (t + 1 < NT) {
#pragma unroll
      for (int j = 0; j < 2; ++j)
#pragma unroll
        for (int r = 0; r < 4; ++r)
          st[j * 4 + r] = *(const f32x4*)(x2base + (size_t)(kb + KB + 4 * (sbi + 16 * j) + r) * DH);
#pragma unroll
      for (int i = 0; i < 16; ++i)
        unxt[i] = __builtin_nontemporal_load(ub + (size_t)(kb + KB) + (size_t)(2 * i) * LK);
      const uint16_t* qp16 = qmt2 + (((size_t)((t + 1) * 4 + ks) * 2 + h) * 2048 + qrow) * 16;
      qn0 = *(const uint4*)qp16;
      qn1 = *(const uint4*)(qp16 + 8);
    }

    // ---- QK: S^T(32k x 32q) = K(32k x 16d) * Q^T(16d x 32q)
    f32x16 sacc;
#pragma unroll
    for (int i = 0; i < 16; ++i) sacc[i] = 0.f;
    const uint16_t* Krow = Kb + (size_t)(ks * 32 + ln) * KROW + h * 8;
    __builtin_amdgcn_s_setprio(1);
#pragma unroll
    for (int dc = 0; dc < 8; ++dc) {
      bf16x8 af = *(const bf16x8*)(Krow + dc * 16);
      sacc = __builtin_amdgcn_mfma_f32_32x32x16_bf16(af, qf[dc].v, sacc, 0, 0, 0);
    }
    __builtin_amdgcn_s_setprio(0);

    // ---- add qm*LOG2E (bf16 pre-packed in fragment order)
#define ADDQM(W, I) { sacc[I] += __uint_as_float((W) << 16); \
                      sacc[I + 1] += __uint_as_float((W) & 0xffff0000u); }
    ADDQM(qc0.x, 0)  ADDQM(qc0.y, 2)  ADDQM(qc0.z, 4)  ADDQM(qc0.w, 6)
    ADDQM(qc1.x, 8)  ADDQM(qc1.y, 10) ADDQM(qc1.z, 12) ADDQM(qc1.w, 14)
#undef ADDQM

    // ---- online softmax (log2 domain; lane owns q-row)
    float pm = sacc[0];
#pragma unroll
    for (int i = 1; i < 16; ++i) pm = fmaxf(pm, sacc[i]);
    pm = fmaxf(pm, __shfl_xor(pm, 32));
    const float mnew = fmaxf(m_run, pm);
    const float resc = __builtin_amdgcn_exp2f(m_run - mnew);
    m_run = mnew;
    float rs = 0.f;
#pragma unroll
    for (int i = 0; i < 16; ++i) {
      sacc[i] = __builtin_amdgcn_exp2f(sacc[i] - mnew);
      rs += sacc[i];
    }
    rs += __shfl_xor(rs, 32);
    l_run = l_run * resc + rs;          // denominator WITHOUT dropout

    // ---- dropout keep-bits via ballot (coalesced u already in regs)
    uint32_t M = 0;
#pragma unroll
    for (int i = 0; i < 16; ++i) {
      unsigned long long bi = __ballot(ucur[i] >= 0.1f);
      uint32_t sel = (ln & 1) ? (uint32_t)(bi >> 32) : (uint32_t)bi;
      M = ((ln >> 1) == i) ? sel : M;
    }
#pragma unroll
    for (int g = 0; g < 4; ++g)
#pragma unroll
      for (int j2 = 0; j2 < 4; ++j2) {
        const uint32_t keep = (M >> (h * 4 + g * 8 + j2)) & 1u;
        sacc[g * 4 + j2] = keep ? sacc[g * 4 + j2] : 0.f;
      }

    // ---- pack bf16 pairs + exchange key-halves across lane-32 boundary
    uint32_t pr[4][2], sw[4][2];
#pragma unroll
    for (int g = 0; g < 4; ++g) {
      pr[g][0] = pack2_bf16(sacc[4 * g + 0], sacc[4 * g + 1]);
      pr[g][1] = pack2_bf16(sacc[4 * g + 2], sacc[4 * g + 3]);
      sw[g][0] = __shfl_xor(pr[g][0], 32);
      sw[g][1] = __shfl_xor(pr[g][1], 32);
    }
    FragAB bfr[2];
#pragma unroll
    for (int c = 0; c < 2; ++c) {
      bfr[c].u[0] = h ? sw[2 * c + 1][0] : pr[2 * c][0];
      bfr[c].u[1] = h ? sw[2 * c + 1][1] : pr[2 * c][1];
      bfr[c].u[2] = h ? pr[2 * c + 1][0] : sw[2 * c][0];
      bfr[c].u[3] = h ? pr[2 * c + 1][1] : sw[2 * c][1];
    }

    // ---- rescale running accumulator
#pragma unroll
    for (int d2 = 0; d2 < 4; ++d2)
#pragma unroll
      for (int i = 0; i < 16; ++i) acco[d2][i] *= resc;

    // ---- PV: out^T(32d x 32q) += V^T(32d x 16k) * P(16k x 32q)
    __builtin_amdgcn_s_setprio(1);
#pragma unroll
    for (int d2 = 0; d2 < 4; ++d2) {
#pragma unroll
      for (int c = 0; c < 2; ++c) {
        const size_t voff = (((size_t)(d2 * 32 + ln)) * KROW + ks * 32 + h * 8 + c * 16) ^ (size_t)vxor;
        bf16x8 av = *(const bf16x8*)(Vb + voff);
        acco[d2] = __builtin_amdgcn_mfma_f32_32x32x16_bf16(av, bfr[c].v, acco[d2], 0, 0, 0);
      }
    }
    __builtin_amdgcn_s_setprio(0);

    // ---- write next tile into other buffer, single barrier per iter
    if (t + 1 < NT) {
      stage_writes(ldsK[cb ^ 1], ldsV[cb ^ 1], st, sbi, sbj);
#pragma unroll
      for (int i = 0; i < 16; ++i) ucur[i] = unxt[i];
      qc0 = qn0; qc1 = qn1;
    }
    __syncthreads();
  }

  // ---- k-split merge through LDS
  float* scr = (wv < 4) ? ((float*)ldsK + (size_t)wv * 4224)
                        : ((float*)ldsV + (size_t)(wv - 4) * 4224);
  scr[lane]      = m_run;
  scr[64 + lane] = l_run;
#pragma unroll
  for (int d2 = 0; d2 < 4; ++d2)
#pragma unroll
    for (int g = 0; g < 4; ++g) {
      f32x4 vv;
#pragma unroll
      for (int j2 = 0; j2 < 4; ++j2) vv[j2] = acco[d2][g * 4 + j2];
      *(f32x4*)(scr + 128 + (size_t)(d2 * 4 + g) * 256 + lane * 4) = vv;
    }
  __syncthreads();

  if (wv < 2) {
    const float* rg[4];
#pragma unroll
    for (int s2 = 0; s2 < 4; ++s2) {
      const int r = qsub + 2 * s2;
      rg[s2] = (r < 4) ? ((const float*)ldsK + (size_t)r * 4224)
                       : ((const float*)ldsV + (size_t)(r - 4) * 4224);
    }
    const float ms0 = rg[0][lane], ms1 = rg[1][lane], ms2 = rg[2][lane], ms3 = rg[3][lane];
    const float ls0 = rg[0][64 + lane], ls1 = rg[1][64 + lane];
    const float ls2 = rg[2][64 + lane], ls3 = rg[3][64 + lane];
    const float mM = fmaxf(fmaxf(ms0, ms1), fmaxf(ms2, ms3));
    const float e0 = __builtin_amdgcn_exp2f(ms0 - mM);
    const float e1 = __builtin_amdgcn_exp2f(ms1 - mM);
    const float e2 = __builtin_amdgcn_exp2f(ms2 - mM);
    const float e3 = __builtin_amdgcn_exp2f(ms3 - mM);
    const float lM = e0 * ls0 + e1 * ls1 + e2 * ls2 + e3 * ls3;
    const float inv = (1.0f / 0.9f) / lM;   // fold dropout 1/(1-p) into normalization
    float* op = out + ((size_t)(b * LQ + qblk * BQ + qsub * 32 + lane % 32)) * DH;
    (void)op;
    const int lq = lane & 31;
    float* op2 = out + ((size_t)(b * LQ + qblk * BQ + qsub * 32 + lq)) * DH;
    const int hh = lane >> 5;
#pragma unroll
    for (int d2 = 0; d2 < 4; ++d2)
#pragma unroll
      for (int g = 0; g < 4; ++g) {
        const size_t off = 128 + (size_t)(d2 * 4 + g) * 256 + lane * 4;
        f32x4 a4 = e0 * *(const f32x4*)(rg[0] + off)
                 + e1 * *(const f32x4*)(rg[1] + off)
                 + e2 * *(const f32x4*)(rg[2] + off)
                 + e3 * *(const f32x4*)(rg[3] + off);
        a4 = a4 * inv;
        *(f32x4*)(op2 + d2 * 32 + 8 * g + 4 * hh) = a4;
      }
  }
}

extern "C" void kernel_launch(void* const* d_in, const int* in_sizes, int n_in,
                              void* d_out, int out_size, void* d_ws, size_t ws_size,
                              hipStream_t stream) {
  (void)in_sizes; (void)n_in; (void)out_size; (void)ws_size;
  const float* x1 = (const float*)d_in[0];
  const float* x2 = (const float*)d_in[1];
  const float* qm = (const float*)d_in[2];
  const float* u  = (const float*)d_in[3];
  float* out = (float*)d_out;

  uint16_t* qmt2 = (uint16_t*)d_ws;   // 8 MB

  qmt_kernel<<<dim3(512), dim3(256), 0, stream>>>(qm, qmt2);
  fattn_kernel<<<dim3(256), dim3(512), 0, stream>>>(x1, x2, u, qmt2, out);
}